// Round 1
// baseline (1829.034 us; speedup 1.0000x reference)
//
#include <hip/hip_runtime.h>
#include <cstdint>
#include <cstddef>

// MambaConv1DTest — single persistent-kernel pipeline.
//
// R1 theory: previous 10-dispatch version's kernels are each <328us (only the
// harness's 2GiB workspace poison fills show in top-5 rocprof rows), yet total
// dur=966us vs ~255us ideal traffic. Collapse everything into ONE kernel with
// device-wide barriers: removes all inter-dispatch overhead, cuts traffic
// 1.61->1.47 GB (qc round-trip eliminated; silu-amax and pool re-conv from qx),
// and makes qx strictly block-local (no cross-XCD data except 4KB bm partials
// + 128KB pooled, which go through fenced barriers).
//
// Occupancy arithmetic for the hand-rolled grid barrier (guaranteed resident):
//   1024 blocks x 256 thr, __launch_bounds__(256,4) -> <=128 VGPR;
//   LDS 33.8KB <= 40.96KB -> 4 blocks/CU x 256 CU = 1024. Exclusive GPU.
// Barrier: device-scope atomic counter + __threadfence (agent release: L2 wb;
// acquire: L2 inv) — same cross-XCD visibility contract the multi-kernel
// version relied on at dispatch boundaries.

static constexpr int BB = 32, CC = 1024, LL = 4096, NCLS = 10;
static constexpr long long NTOT = 1LL * BB * CC * LL;   // 134,217,728
static constexpr int ROWS = BB * CC;                     // 32768
static constexpr int NB = 1024;                          // grid; NB == CC required
static_assert(NB == CC, "block==channel mapping requires NB==CC");

// workspace float offsets (bytes 0..255 = barrier counter, zeroed via memset)
static constexpr int OF_BM0 = 64;      // 1024
static constexpr int OF_BM1 = 1088;    // 1024
static constexpr int OF_BM2 = 2112;    // 1024
static constexpr int OF_BM3 = 3136;    // 1024
static constexpr int OF_POOL = 4160;   // 32768
static constexpr size_t OFFQ = 36928ull * 4ull;  // 147712 B, 16B aligned

__device__ __forceinline__ float qlvl_mul(float x, float rs) {
  return fminf(fmaxf(rintf(x * rs), -128.f), 127.f);
}
__device__ __forceinline__ float qlvl_div(float x, float s) {
  return fminf(fmaxf(rintf(x / s), -128.f), 127.f);
}
__device__ __forceinline__ float fq_div(float x, float s) {
  return qlvl_div(x, s) * s;
}
__device__ __forceinline__ float wred_sum(float s) {
#pragma unroll
  for (int o = 32; o; o >>= 1) s += __shfl_xor(s, o);
  return s;
}

// block max-reduce via LDS tree; all threads get result; redS reusable after.
__device__ __forceinline__ float bred_max(float v, float* redS) {
  int t = threadIdx.x;
  redS[t] = v; __syncthreads();
  for (int s = 128; s; s >>= 1) { if (t < s) redS[t] = fmaxf(redS[t], redS[t + s]); __syncthreads(); }
  float r = redS[0]; __syncthreads();
  return r;
}

// grid barrier: release-fence, arrive, spin, acquire-fence.
__device__ __forceinline__ void gbar(unsigned* cnt, unsigned target) {
  __syncthreads();                 // drains this block's vmem (compiler waitcnt)
  __threadfence();                 // agent release: push L2 -> coherence point
  if (threadIdx.x == 0) {
    atomicAdd(cnt, 1u);
    unsigned spins = 0;
    while (__hip_atomic_load(cnt, __ATOMIC_RELAXED, __HIP_MEMORY_SCOPE_AGENT) < target) {
      __builtin_amdgcn_s_sleep(16);
      if (++spins > 20000000u) break;   // catastrophic-only bailout (no legit wait is >ms)
    }
  }
  __syncthreads();                 // everyone behind the arrival point
  __threadfence();                 // agent acquire: invalidate stale L2 lines
}

__global__ __launch_bounds__(256, 4) void mega_k(
    const float* __restrict__ x, const float* __restrict__ cw, const float* __restrict__ cb,
    const float* __restrict__ lw, const float* __restrict__ lb,
    float* __restrict__ out, float* __restrict__ wsf, signed char* __restrict__ qx,
    unsigned* __restrict__ cnt) {
  __shared__ float lutR[256 * 32];
  __shared__ float redS[256];
  const int tid = threadIdx.x, blk = blockIdx.x;
  const int t31 = tid & 31, lane = tid & 63, wid = tid >> 6;

  // ---- ph0: weight amaxes (redundant per block; max is order-invariant, L2-hit)
  float acw = 0.f;
#pragma unroll
  for (int i = 0; i < 16; ++i) acw = fmaxf(acw, fabsf(cw[tid + 256 * i]));
  acw = bred_max(acw, redS);
  float alw = 0.f;
  for (int i = tid; i < NCLS * CC; i += 256) alw = fmaxf(alw, fabsf(lw[i]));
  alw = bred_max(alw, redS);
  const float s_w = acw / 127.f + 1e-8f;
  const float s_l = alw / 127.f + 1e-8f;

  // ---- ph1: amax(x) over 536 MB (float4 grid-stride)
  {
    const float4* p4 = (const float4*)x;
    float m = 0.f;
    const long long n4 = NTOT / 4, stride = (long long)NB * 256;
    for (long long i = (long long)blk * 256 + tid; i < n4; i += stride) {
      float4 v = p4[i];
      m = fmaxf(m, fmaxf(fmaxf(fabsf(v.x), fabsf(v.y)), fmaxf(fabsf(v.z), fabsf(v.w))));
    }
    m = bred_max(m, redS);
    if (!tid) wsf[OF_BM0 + blk] = m;
  }
  gbar(cnt, 1u * NB);
  float m = fmaxf(fmaxf(wsf[OF_BM0 + tid], wsf[OF_BM0 + tid + 256]),
                  fmaxf(wsf[OF_BM0 + tid + 512], wsf[OF_BM0 + tid + 768]));
  const float amax_x = bred_max(m, redS);
  const float s_x = amax_x / 127.f + 1e-8f, rs_x = 1.f / s_x;
  const float s_xw = s_x * s_w;

  // block == channel: weights quantized once into registers for ph2/ph3/ph4
  const int c = blk;
  const float wl0 = qlvl_div(cw[c * 4 + 0], s_w), wl1 = qlvl_div(cw[c * 4 + 1], s_w);
  const float wl2 = qlvl_div(cw[c * 4 + 2], s_w), wl3 = qlvl_div(cw[c * 4 + 3], s_w);
  const float bc = cb[c];

  // ---- ph2: quantize x -> qx (block-local rows), conv, amax|h|
  {
    float mH = 0.f;
    const int t0 = tid * 16;
    for (int k = 0; k < BB; ++k) {
      const int row = blk + (k << 10);            // c = row & 1023 == blk
      const float* xr = x + 1LL * row * LL;
      float lv[19];
      if (t0 == 0) { lv[0] = 0.f; lv[1] = 0.f; lv[2] = 0.f; }
      else {
        float4 p = *(const float4*)(xr + t0 - 4);
        lv[0] = qlvl_mul(p.y, rs_x); lv[1] = qlvl_mul(p.z, rs_x); lv[2] = qlvl_mul(p.w, rs_x);
      }
#pragma unroll
      for (int jj = 0; jj < 4; ++jj) {
        float4 v = *(const float4*)(xr + t0 + 4 * jj);
        lv[3 + 4 * jj] = qlvl_mul(v.x, rs_x); lv[4 + 4 * jj] = qlvl_mul(v.y, rs_x);
        lv[5 + 4 * jj] = qlvl_mul(v.z, rs_x); lv[6 + 4 * jj] = qlvl_mul(v.w, rs_x);
      }
      union { int4 v; signed char ch[16]; } pk;
#pragma unroll
      for (int j = 0; j < 16; ++j) {
        pk.ch[j] = (signed char)(int)lv[3 + j];
        float sum = lv[j] * wl0 + lv[j + 1] * wl1 + lv[j + 2] * wl2 + lv[j + 3] * wl3; // exact ints in fp32
        float h = fmaf(s_xw, sum, bc);
        mH = fmaxf(mH, fabsf(h));
      }
      if (qx) *(int4*)(qx + 1LL * row * LL + t0) = pk.v;
    }
    mH = bred_max(mH, redS);
    if (!tid) wsf[OF_BM1 + blk] = mH;
  }
  gbar(cnt, 2u * NB);
  m = fmaxf(fmaxf(wsf[OF_BM1 + tid], wsf[OF_BM1 + tid + 256]),
            fmaxf(wsf[OF_BM1 + tid + 512], wsf[OF_BM1 + tid + 768]));
  const float amax_h = bred_max(m, redS);
  const float s_c = amax_h / 127.f + 1e-8f, rs_c = 1.f / s_c;

  // build absY LUT (replicated 32x, conflict-free)
  {
    float v = (float)(tid - 128) * s_c;
    float y = v * (1.f / (1.f + expf(-v)));
    float ay = fabsf(y);
#pragma unroll
    for (int r = 0; r < 32; ++r) lutR[tid * 32 + r] = ay;
  }
  __syncthreads();

  // ---- ph3: amax|silu(fq(h))| from qx (same block-local rows; no qc store)
  {
    float mS = 0.f;
    const int t0 = tid * 16;
    for (int k = 0; k < BB; ++k) {
      const int row = blk + (k << 10);
      float lv[19];
      if (qx) {
        const signed char* qr = qx + 1LL * row * LL;
        if (t0 == 0) { lv[0] = 0.f; lv[1] = 0.f; lv[2] = 0.f; }
        else {
          int pv = *(const int*)(qr + t0 - 4);
          lv[0] = (float)((signed char)(pv >> 8));
          lv[1] = (float)((signed char)(pv >> 16));
          lv[2] = (float)(pv >> 24);
        }
        union { int4 v; signed char ch[16]; } in; in.v = *(const int4*)(qr + t0);
#pragma unroll
        for (int j = 0; j < 16; ++j) lv[3 + j] = (float)in.ch[j];
      } else {
        const float* xr = x + 1LL * row * LL;
        if (t0 == 0) { lv[0] = 0.f; lv[1] = 0.f; lv[2] = 0.f; }
        else {
          float4 p = *(const float4*)(xr + t0 - 4);
          lv[0] = qlvl_mul(p.y, rs_x); lv[1] = qlvl_mul(p.z, rs_x); lv[2] = qlvl_mul(p.w, rs_x);
        }
#pragma unroll
        for (int jj = 0; jj < 4; ++jj) {
          float4 v = *(const float4*)(xr + t0 + 4 * jj);
          lv[3 + 4 * jj] = qlvl_mul(v.x, rs_x); lv[4 + 4 * jj] = qlvl_mul(v.y, rs_x);
          lv[5 + 4 * jj] = qlvl_mul(v.z, rs_x); lv[6 + 4 * jj] = qlvl_mul(v.w, rs_x);
        }
      }
#pragma unroll
      for (int j = 0; j < 16; ++j) {
        float sum = lv[j] * wl0 + lv[j + 1] * wl1 + lv[j + 2] * wl2 + lv[j + 3] * wl3;
        float h = fmaf(s_xw, sum, bc);
        float qf = fminf(fmaxf(rintf(h * rs_c), -128.f), 127.f);
        mS = fmaxf(mS, lutR[((int)qf + 128) * 32 + t31]);
      }
    }
    mS = bred_max(mS, redS);
    if (!tid) wsf[OF_BM2 + blk] = mS;
  }
  gbar(cnt, 3u * NB);
  m = fmaxf(fmaxf(wsf[OF_BM2 + tid], wsf[OF_BM2 + tid + 256]),
            fmaxf(wsf[OF_BM2 + tid + 512], wsf[OF_BM2 + tid + 768]));
  const float amax_y = bred_max(m, redS);

  // build pool LUT lut2 (verbatim finL_k math), overwrite lutR
  {
    float s1 = amax_y / 127.f + 1e-8f;
    float maxj = fminf(fmaxf(rintf(amax_y / s1), -128.f), 127.f);
    float s2 = (maxj * s1) / 127.f + 1e-8f;
    float v = (float)(tid - 128) * s_c;
    float y = v * (1.f / (1.f + expf(-v)));
    float y1 = fq_div(y, s1);
    float l2v = fq_div(y1, s2);
    __syncthreads();
#pragma unroll
    for (int r = 0; r < 32; ++r) lutR[tid * 32 + r] = l2v;
  }
  __syncthreads();

  // ---- ph4: mean-pool. One wave per row, p-major/k-minor order + 64-lane
  // butterfly sum = byte-identical to the validated p5_k summation.
  {
    float pm = 0.f;
    for (int k = 0; k < 8; ++k) {
      const int row = blk + ((wid + 4 * k) << 10);  // same block-local row set
      const signed char* qr = qx ? qx + 1LL * row * LL : nullptr;
      const float* xr = x + 1LL * row * LL;
      float sum = 0.f;
#pragma unroll
      for (int p = 0; p < 4; ++p) {
        const int t0 = p * 1024 + lane * 16;
        float lv[19];
        if (qx) {
          if (t0 == 0) { lv[0] = 0.f; lv[1] = 0.f; lv[2] = 0.f; }
          else {
            int pv = *(const int*)(qr + t0 - 4);
            lv[0] = (float)((signed char)(pv >> 8));
            lv[1] = (float)((signed char)(pv >> 16));
            lv[2] = (float)(pv >> 24);
          }
          union { int4 v; signed char ch[16]; } in; in.v = *(const int4*)(qr + t0);
#pragma unroll
          for (int j = 0; j < 16; ++j) lv[3 + j] = (float)in.ch[j];
        } else {
          if (t0 == 0) { lv[0] = 0.f; lv[1] = 0.f; lv[2] = 0.f; }
          else {
            float4 pp = *(const float4*)(xr + t0 - 4);
            lv[0] = qlvl_mul(pp.y, rs_x); lv[1] = qlvl_mul(pp.z, rs_x); lv[2] = qlvl_mul(pp.w, rs_x);
          }
#pragma unroll
          for (int jj = 0; jj < 4; ++jj) {
            float4 v = *(const float4*)(xr + t0 + 4 * jj);
            lv[3 + 4 * jj] = qlvl_mul(v.x, rs_x); lv[4 + 4 * jj] = qlvl_mul(v.y, rs_x);
            lv[5 + 4 * jj] = qlvl_mul(v.z, rs_x); lv[6 + 4 * jj] = qlvl_mul(v.w, rs_x);
          }
        }
#pragma unroll
        for (int j = 0; j < 16; ++j) {
          float s4 = lv[j] * wl0 + lv[j + 1] * wl1 + lv[j + 2] * wl2 + lv[j + 3] * wl3;
          float h = fmaf(s_xw, s4, bc);
          float qf = fminf(fmaxf(rintf(h * rs_c), -128.f), 127.f);
          sum += lutR[((int)qf + 128) * 32 + t31];
        }
      }
      sum = wred_sum(sum);
      if (lane == 0) {
        float pv = sum * (1.f / (float)LL);
        wsf[OF_POOL + row] = pv;
        pm = fmaxf(pm, fabsf(pv));
      }
    }
    pm = bred_max(pm, redS);
    if (!tid) wsf[OF_BM3 + blk] = pm;
  }
  gbar(cnt, 4u * NB);
  m = fmaxf(fmaxf(wsf[OF_BM3 + tid], wsf[OF_BM3 + tid + 256]),
            fmaxf(wsf[OF_BM3 + tid + 512], wsf[OF_BM3 + tid + 768]));
  const float aP = bred_max(m, redS);

  // ---- ph5: head (blocks 0..319), verbatim head_k structure
  if (blk < BB * NCLS) {
    const float s_p = aP / 127.f + 1e-8f;
    const int b = blk / NCLS, n = blk - b * NCLS;
    float sum = 0.f;
    for (int ci = tid; ci < CC; ci += 256)
      sum += fq_div(wsf[OF_POOL + b * CC + ci], s_p) * fq_div(lw[n * CC + ci], s_l);
    redS[tid] = sum; __syncthreads();
    for (int s = 128; s; s >>= 1) { if (tid < s) redS[tid] += redS[tid + s]; __syncthreads(); }
    if (!tid) out[b * NCLS + n] = redS[0] + lb[n];
  }
}

extern "C" void kernel_launch(void* const* d_in, const int* in_sizes, int n_in,
                              void* d_out, int out_size, void* d_ws, size_t ws_size,
                              hipStream_t stream) {
  const float* x  = (const float*)d_in[0];
  const float* cw = (const float*)d_in[1];
  const float* cb = (const float*)d_in[2];
  const float* lw = (const float*)d_in[3];
  const float* lb = (const float*)d_in[4];
  float* wsf = (float*)d_ws;
  unsigned* cnt = (unsigned*)d_ws;
  signed char* qx = (ws_size >= OFFQ + (size_t)NTOT) ? (signed char*)d_ws + OFFQ
                                                     : (signed char*)nullptr;
  // zero barrier counter region (workspace is poisoned between iterations)
  hipMemsetAsync(d_ws, 0, 256, stream);
  hipLaunchKernelGGL(mega_k, dim3(NB), dim3(256), 0, stream,
                     x, cw, cb, lw, lb, (float*)d_out, wsf, qx, cnt);
}

// Round 2
// 1099.697 us; speedup vs baseline: 1.6632x; 1.6632x over previous
//
#include <hip/hip_runtime.h>
#include <cstdint>
#include <cstddef>

// MambaConv1DTest — single persistent-kernel pipeline, fence-free barriers.
//
// R2 theory: R1's mega_k ran 1322us at 612 GB/s with VALUBusy 11% — stalled,
// not BW-bound. Cause: __threadfence() in gbar = buffer_wbl2 + buffer_inv
// (full L2 writeback + invalidate) executed by ALL 4096 waves at each of 4
// barriers, serializing on the L2 flush queue and nuking L2 reuse of x/qx.
// Only 132KB of data (bm partials + pooled) actually crosses blocks; qx is
// strictly block-local (same CU/L2, write-through L1, never read-before-write).
// Fix: cross-block values travel via device-scope RELAXED ATOMIC stores/loads
// (executed at the coherence point — no L1/L2 flush needed); gbar is
// syncthreads + relaxed atomic arrive/spin. __syncthreads() already drains
// each wave's vmem (compiler emits s_waitcnt vmcnt(0) before s_barrier), so
// all the block's atomic stores are globally visible before thread 0 arrives.
// No fences anywhere in the hot path. Numerics bit-identical to R1 (absmax=0).

static constexpr int BB = 32, CC = 1024, LL = 4096, NCLS = 10;
static constexpr long long NTOT = 1LL * BB * CC * LL;   // 134,217,728
static constexpr int ROWS = BB * CC;                     // 32768
static constexpr int NB = 1024;                          // grid; NB == CC required
static_assert(NB == CC, "block==channel mapping requires NB==CC");

// workspace float offsets (bytes 0..255 = barrier counter, zeroed via memset)
static constexpr int OF_BM0 = 64;      // 1024
static constexpr int OF_BM1 = 1088;    // 1024
static constexpr int OF_BM2 = 2112;    // 1024
static constexpr int OF_BM3 = 3136;    // 1024
static constexpr int OF_POOL = 4160;   // 32768
static constexpr size_t OFFQ = 36928ull * 4ull;  // 147712 B, 16B aligned

__device__ __forceinline__ float qlvl_mul(float x, float rs) {
  return fminf(fmaxf(rintf(x * rs), -128.f), 127.f);
}
__device__ __forceinline__ float qlvl_div(float x, float s) {
  return fminf(fmaxf(rintf(x / s), -128.f), 127.f);
}
__device__ __forceinline__ float fq_div(float x, float s) {
  return qlvl_div(x, s) * s;
}
__device__ __forceinline__ float wred_sum(float s) {
#pragma unroll
  for (int o = 32; o; o >>= 1) s += __shfl_xor(s, o);
  return s;
}

// device-scope (coherence-point) relaxed atomic transport for cross-block data
__device__ __forceinline__ void gput(float* p, float v) {
  __hip_atomic_store(p, v, __ATOMIC_RELAXED, __HIP_MEMORY_SCOPE_AGENT);
}
__device__ __forceinline__ float gget(const float* p) {
  return __hip_atomic_load(p, __ATOMIC_RELAXED, __HIP_MEMORY_SCOPE_AGENT);
}

// block max-reduce via LDS tree; all threads get result; redS reusable after.
__device__ __forceinline__ float bred_max(float v, float* redS) {
  int t = threadIdx.x;
  redS[t] = v; __syncthreads();
  for (int s = 128; s; s >>= 1) { if (t < s) redS[t] = fmaxf(redS[t], redS[t + s]); __syncthreads(); }
  float r = redS[0]; __syncthreads();
  return r;
}

// fence-free grid barrier. Entry __syncthreads drains every wave's vmem
// (compiler-emitted vmcnt(0) before s_barrier), so all agent-scope atomic
// stores issued by this block are complete at the coherence point before
// thread 0 arrives. Readers after the barrier use agent-scope atomic loads.
__device__ __forceinline__ void gbar(unsigned* cnt, unsigned target) {
  __syncthreads();
  if (threadIdx.x == 0) {
    __hip_atomic_fetch_add(cnt, 1u, __ATOMIC_RELAXED, __HIP_MEMORY_SCOPE_AGENT);
    unsigned spins = 0;
    while (__hip_atomic_load(cnt, __ATOMIC_RELAXED, __HIP_MEMORY_SCOPE_AGENT) < target) {
      __builtin_amdgcn_s_sleep(8);
      if (++spins > 40000000u) break;   // catastrophic-only bailout
    }
  }
  __syncthreads();
}

__global__ __launch_bounds__(256, 4) void mega_k(
    const float* __restrict__ x, const float* __restrict__ cw, const float* __restrict__ cb,
    const float* __restrict__ lw, const float* __restrict__ lb,
    float* __restrict__ out, float* __restrict__ wsf, signed char* __restrict__ qx,
    unsigned* __restrict__ cnt) {
  __shared__ float lutR[256 * 32];
  __shared__ float redS[256];
  const int tid = threadIdx.x, blk = blockIdx.x;
  const int t31 = tid & 31, lane = tid & 63, wid = tid >> 6;

  // ---- ph0: weight amaxes (redundant per block; max is order-invariant, L2-hit)
  float acw = 0.f;
#pragma unroll
  for (int i = 0; i < 16; ++i) acw = fmaxf(acw, fabsf(cw[tid + 256 * i]));
  acw = bred_max(acw, redS);
  float alw = 0.f;
  for (int i = tid; i < NCLS * CC; i += 256) alw = fmaxf(alw, fabsf(lw[i]));
  alw = bred_max(alw, redS);
  const float s_w = acw / 127.f + 1e-8f;
  const float s_l = alw / 127.f + 1e-8f;

  // ---- ph1: amax(x) over 536 MB (float4 grid-stride)
  {
    const float4* p4 = (const float4*)x;
    float m = 0.f;
    const long long n4 = NTOT / 4, stride = (long long)NB * 256;
    for (long long i = (long long)blk * 256 + tid; i < n4; i += stride) {
      float4 v = p4[i];
      m = fmaxf(m, fmaxf(fmaxf(fabsf(v.x), fabsf(v.y)), fmaxf(fabsf(v.z), fabsf(v.w))));
    }
    m = bred_max(m, redS);
    if (!tid) gput(&wsf[OF_BM0 + blk], m);
  }
  gbar(cnt, 1u * NB);
  float m = fmaxf(fmaxf(gget(&wsf[OF_BM0 + tid]), gget(&wsf[OF_BM0 + tid + 256])),
                  fmaxf(gget(&wsf[OF_BM0 + tid + 512]), gget(&wsf[OF_BM0 + tid + 768])));
  const float amax_x = bred_max(m, redS);
  const float s_x = amax_x / 127.f + 1e-8f, rs_x = 1.f / s_x;
  const float s_xw = s_x * s_w;

  // block == channel: weights quantized once into registers for ph2/ph3/ph4
  const int c = blk;
  const float wl0 = qlvl_div(cw[c * 4 + 0], s_w), wl1 = qlvl_div(cw[c * 4 + 1], s_w);
  const float wl2 = qlvl_div(cw[c * 4 + 2], s_w), wl3 = qlvl_div(cw[c * 4 + 3], s_w);
  const float bc = cb[c];

  // ---- ph2: quantize x -> qx (block-local rows), conv, amax|h|
  {
    float mH = 0.f;
    const int t0 = tid * 16;
    for (int k = 0; k < BB; ++k) {
      const int row = blk + (k << 10);            // c = row & 1023 == blk
      const float* xr = x + 1LL * row * LL;
      float lv[19];
      if (t0 == 0) { lv[0] = 0.f; lv[1] = 0.f; lv[2] = 0.f; }
      else {
        float4 p = *(const float4*)(xr + t0 - 4);
        lv[0] = qlvl_mul(p.y, rs_x); lv[1] = qlvl_mul(p.z, rs_x); lv[2] = qlvl_mul(p.w, rs_x);
      }
#pragma unroll
      for (int jj = 0; jj < 4; ++jj) {
        float4 v = *(const float4*)(xr + t0 + 4 * jj);
        lv[3 + 4 * jj] = qlvl_mul(v.x, rs_x); lv[4 + 4 * jj] = qlvl_mul(v.y, rs_x);
        lv[5 + 4 * jj] = qlvl_mul(v.z, rs_x); lv[6 + 4 * jj] = qlvl_mul(v.w, rs_x);
      }
      union { int4 v; signed char ch[16]; } pk;
#pragma unroll
      for (int j = 0; j < 16; ++j) {
        pk.ch[j] = (signed char)(int)lv[3 + j];
        float sum = lv[j] * wl0 + lv[j + 1] * wl1 + lv[j + 2] * wl2 + lv[j + 3] * wl3; // exact ints in fp32
        float h = fmaf(s_xw, sum, bc);
        mH = fmaxf(mH, fabsf(h));
      }
      if (qx) *(int4*)(qx + 1LL * row * LL + t0) = pk.v;
    }
    mH = bred_max(mH, redS);
    if (!tid) gput(&wsf[OF_BM1 + blk], mH);
  }
  gbar(cnt, 2u * NB);
  m = fmaxf(fmaxf(gget(&wsf[OF_BM1 + tid]), gget(&wsf[OF_BM1 + tid + 256])),
            fmaxf(gget(&wsf[OF_BM1 + tid + 512]), gget(&wsf[OF_BM1 + tid + 768])));
  const float amax_h = bred_max(m, redS);
  const float s_c = amax_h / 127.f + 1e-8f, rs_c = 1.f / s_c;

  // build absY LUT (replicated 32x, conflict-free)
  {
    float v = (float)(tid - 128) * s_c;
    float y = v * (1.f / (1.f + expf(-v)));
    float ay = fabsf(y);
#pragma unroll
    for (int r = 0; r < 32; ++r) lutR[tid * 32 + r] = ay;
  }
  __syncthreads();

  // ---- ph3: amax|silu(fq(h))| from qx (same block-local rows; no qc store)
  {
    float mS = 0.f;
    const int t0 = tid * 16;
    for (int k = 0; k < BB; ++k) {
      const int row = blk + (k << 10);
      float lv[19];
      if (qx) {
        const signed char* qr = qx + 1LL * row * LL;
        if (t0 == 0) { lv[0] = 0.f; lv[1] = 0.f; lv[2] = 0.f; }
        else {
          int pv = *(const int*)(qr + t0 - 4);
          lv[0] = (float)((signed char)(pv >> 8));
          lv[1] = (float)((signed char)(pv >> 16));
          lv[2] = (float)(pv >> 24);
        }
        union { int4 v; signed char ch[16]; } in; in.v = *(const int4*)(qr + t0);
#pragma unroll
        for (int j = 0; j < 16; ++j) lv[3 + j] = (float)in.ch[j];
      } else {
        const float* xr = x + 1LL * row * LL;
        if (t0 == 0) { lv[0] = 0.f; lv[1] = 0.f; lv[2] = 0.f; }
        else {
          float4 p = *(const float4*)(xr + t0 - 4);
          lv[0] = qlvl_mul(p.y, rs_x); lv[1] = qlvl_mul(p.z, rs_x); lv[2] = qlvl_mul(p.w, rs_x);
        }
#pragma unroll
        for (int jj = 0; jj < 4; ++jj) {
          float4 v = *(const float4*)(xr + t0 + 4 * jj);
          lv[3 + 4 * jj] = qlvl_mul(v.x, rs_x); lv[4 + 4 * jj] = qlvl_mul(v.y, rs_x);
          lv[5 + 4 * jj] = qlvl_mul(v.z, rs_x); lv[6 + 4 * jj] = qlvl_mul(v.w, rs_x);
        }
      }
#pragma unroll
      for (int j = 0; j < 16; ++j) {
        float sum = lv[j] * wl0 + lv[j + 1] * wl1 + lv[j + 2] * wl2 + lv[j + 3] * wl3;
        float h = fmaf(s_xw, sum, bc);
        float qf = fminf(fmaxf(rintf(h * rs_c), -128.f), 127.f);
        mS = fmaxf(mS, lutR[((int)qf + 128) * 32 + t31]);
      }
    }
    mS = bred_max(mS, redS);
    if (!tid) gput(&wsf[OF_BM2 + blk], mS);
  }
  gbar(cnt, 3u * NB);
  m = fmaxf(fmaxf(gget(&wsf[OF_BM2 + tid]), gget(&wsf[OF_BM2 + tid + 256])),
            fmaxf(gget(&wsf[OF_BM2 + tid + 512]), gget(&wsf[OF_BM2 + tid + 768])));
  const float amax_y = bred_max(m, redS);

  // build pool LUT lut2 (verbatim finL_k math), overwrite lutR
  {
    float s1 = amax_y / 127.f + 1e-8f;
    float maxj = fminf(fmaxf(rintf(amax_y / s1), -128.f), 127.f);
    float s2 = (maxj * s1) / 127.f + 1e-8f;
    float v = (float)(tid - 128) * s_c;
    float y = v * (1.f / (1.f + expf(-v)));
    float y1 = fq_div(y, s1);
    float l2v = fq_div(y1, s2);
    __syncthreads();
#pragma unroll
    for (int r = 0; r < 32; ++r) lutR[tid * 32 + r] = l2v;
  }
  __syncthreads();

  // ---- ph4: mean-pool. One wave per row, p-major/k-minor order + 64-lane
  // butterfly sum = byte-identical to the validated p5_k summation.
  {
    float pm = 0.f;
    for (int k = 0; k < 8; ++k) {
      const int row = blk + ((wid + 4 * k) << 10);  // same block-local row set
      const signed char* qr = qx ? qx + 1LL * row * LL : nullptr;
      const float* xr = x + 1LL * row * LL;
      float sum = 0.f;
#pragma unroll
      for (int p = 0; p < 4; ++p) {
        const int t0 = p * 1024 + lane * 16;
        float lv[19];
        if (qx) {
          if (t0 == 0) { lv[0] = 0.f; lv[1] = 0.f; lv[2] = 0.f; }
          else {
            int pv = *(const int*)(qr + t0 - 4);
            lv[0] = (float)((signed char)(pv >> 8));
            lv[1] = (float)((signed char)(pv >> 16));
            lv[2] = (float)(pv >> 24);
          }
          union { int4 v; signed char ch[16]; } in; in.v = *(const int4*)(qr + t0);
#pragma unroll
          for (int j = 0; j < 16; ++j) lv[3 + j] = (float)in.ch[j];
        } else {
          if (t0 == 0) { lv[0] = 0.f; lv[1] = 0.f; lv[2] = 0.f; }
          else {
            float4 pp = *(const float4*)(xr + t0 - 4);
            lv[0] = qlvl_mul(pp.y, rs_x); lv[1] = qlvl_mul(pp.z, rs_x); lv[2] = qlvl_mul(pp.w, rs_x);
          }
#pragma unroll
          for (int jj = 0; jj < 4; ++jj) {
            float4 v = *(const float4*)(xr + t0 + 4 * jj);
            lv[3 + 4 * jj] = qlvl_mul(v.x, rs_x); lv[4 + 4 * jj] = qlvl_mul(v.y, rs_x);
            lv[5 + 4 * jj] = qlvl_mul(v.z, rs_x); lv[6 + 4 * jj] = qlvl_mul(v.w, rs_x);
          }
        }
#pragma unroll
        for (int j = 0; j < 16; ++j) {
          float s4 = lv[j] * wl0 + lv[j + 1] * wl1 + lv[j + 2] * wl2 + lv[j + 3] * wl3;
          float h = fmaf(s_xw, s4, bc);
          float qf = fminf(fmaxf(rintf(h * rs_c), -128.f), 127.f);
          sum += lutR[((int)qf + 128) * 32 + t31];
        }
      }
      sum = wred_sum(sum);
      if (lane == 0) {
        float pv = sum * (1.f / (float)LL);
        gput(&wsf[OF_POOL + row], pv);
        pm = fmaxf(pm, fabsf(pv));
      }
    }
    pm = bred_max(pm, redS);
    if (!tid) gput(&wsf[OF_BM3 + blk], pm);
  }
  gbar(cnt, 4u * NB);
  m = fmaxf(fmaxf(gget(&wsf[OF_BM3 + tid]), gget(&wsf[OF_BM3 + tid + 256])),
            fmaxf(gget(&wsf[OF_BM3 + tid + 512]), gget(&wsf[OF_BM3 + tid + 768])));
  const float aP = bred_max(m, redS);

  // ---- ph5: head (blocks 0..319), verbatim head_k structure
  if (blk < BB * NCLS) {
    const float s_p = aP / 127.f + 1e-8f;
    const int b = blk / NCLS, n = blk - b * NCLS;
    float sum = 0.f;
    for (int ci = tid; ci < CC; ci += 256)
      sum += fq_div(gget(&wsf[OF_POOL + b * CC + ci]), s_p) * fq_div(lw[n * CC + ci], s_l);
    redS[tid] = sum; __syncthreads();
    for (int s = 128; s; s >>= 1) { if (tid < s) redS[tid] += redS[tid + s]; __syncthreads(); }
    if (!tid) out[b * NCLS + n] = redS[0] + lb[n];
  }
}

extern "C" void kernel_launch(void* const* d_in, const int* in_sizes, int n_in,
                              void* d_out, int out_size, void* d_ws, size_t ws_size,
                              hipStream_t stream) {
  const float* x  = (const float*)d_in[0];
  const float* cw = (const float*)d_in[1];
  const float* cb = (const float*)d_in[2];
  const float* lw = (const float*)d_in[3];
  const float* lb = (const float*)d_in[4];
  float* wsf = (float*)d_ws;
  unsigned* cnt = (unsigned*)d_ws;
  signed char* qx = (ws_size >= OFFQ + (size_t)NTOT) ? (signed char*)d_ws + OFFQ
                                                     : (signed char*)nullptr;
  // zero barrier counter region (workspace is poisoned between iterations)
  hipMemsetAsync(d_ws, 0, 256, stream);
  hipLaunchKernelGGL(mega_k, dim3(NB), dim3(256), 0, stream,
                     x, cw, cb, lw, lb, (float*)d_out, wsf, qx, cnt);
}

// Round 3
// 911.833 us; speedup vs baseline: 2.0059x; 1.2060x over previous
//
#include <hip/hip_runtime.h>
#include <cstdint>
#include <cstddef>

// MambaConv1DTest — single persistent-kernel pipeline, R3.
//
// R3 changes (theory: latency-bound at 48% occupancy + redundant 4th pass):
//  1. Histogram restructure: ph3 builds per-row 256-bin histograms of the
//     conv-quantized levels (LDS ds_add) instead of per-element LUT lookups.
//     silu-amax = max over OCCUPIED bins of absY[bin] (bit-identical set to
//     per-element max). Pooled mean = exact-integer dot  sum(n_i * j2_i),
//     |sum| <= 2^19 (exact fp32), * s2/4096. Removes the entire old ph4 pass
//     over qx (134 MB + 134M-elt conv recompute) and the 32 KB LDS LUT.
//  2. LDS 33.8 -> 17.5 KB and __launch_bounds__(256,8): 8 blocks/CU resident
//     (VGPR cap 64; was 56). Grid doubles to 2048 so the grid barrier still
//     has all blocks resident (runtime occupancy query picks 2048 vs 1024).
//  3. Barrier arrival spread over 32 counters (32B apart) + single release
//     flag per phase; block 0 sums counters, others poll the flag read-only.
//     Avoids 2048 serialized same-address RMWs per barrier.
// Cross-block data still travels via agent-scope relaxed atomics (R2 scheme).

static constexpr int BB = 32, CC = 1024, LL = 4096, NCLS = 10;
static constexpr long long NTOT = 1LL * BB * CC * LL;   // 134,217,728
static constexpr int ROWS = BB * CC;                     // 32768

// ws word layout:
//  [0..255]     32 arrival counters (stride 8 words = 32 B)
//  [256..259]   release flags, phases 0..3
//  [512..2559]  bm0   [2560..4607] bm1   [4608..6655] bm2   [6656..8703] bm3
//  [8704..41471] pooled (32768)
static constexpr int OF_BM0 = 512, OF_BM1 = 2560, OF_BM2 = 4608, OF_BM3 = 6656;
static constexpr int OF_POOL = 8704;
static constexpr size_t OFFQ = 41472ull * 4ull;          // 165,888 B, 16B aligned

__device__ __forceinline__ float qlvl_mul(float x, float rs) {
  return fminf(fmaxf(rintf(x * rs), -128.f), 127.f);
}
__device__ __forceinline__ float qlvl_div(float x, float s) {
  return fminf(fmaxf(rintf(x / s), -128.f), 127.f);
}
__device__ __forceinline__ float fq_div(float x, float s) {
  return qlvl_div(x, s) * s;
}
__device__ __forceinline__ float wred_sum(float s) {
#pragma unroll
  for (int o = 32; o; o >>= 1) s += __shfl_xor(s, o);
  return s;
}
__device__ __forceinline__ void gput(float* p, float v) {
  __hip_atomic_store(p, v, __ATOMIC_RELAXED, __HIP_MEMORY_SCOPE_AGENT);
}
__device__ __forceinline__ float gget(const float* p) {
  return __hip_atomic_load(p, __ATOMIC_RELAXED, __HIP_MEMORY_SCOPE_AGENT);
}

__device__ __forceinline__ float bred_max(float v, float* redS) {
  int t = threadIdx.x;
  redS[t] = v; __syncthreads();
  for (int s = 128; s; s >>= 1) { if (t < s) redS[t] = fmaxf(redS[t], redS[t + s]); __syncthreads(); }
  float r = redS[0]; __syncthreads();
  return r;
}

// Spread-arrival grid barrier. Entry __syncthreads drains this block's vmem
// (compiler vmcnt(0) before s_barrier) => its agent-scope atomic stores are
// globally visible before arrival. Targets are cumulative ((phase+1)*nb).
__device__ __forceinline__ void gbar(unsigned* wsu, int phase, unsigned target, int blk) {
  __syncthreads();
  if (threadIdx.x == 0) {
    __hip_atomic_fetch_add(&wsu[(blk & 31) * 8], 1u, __ATOMIC_RELAXED, __HIP_MEMORY_SCOPE_AGENT);
    unsigned spins = 0;
    if (blk == 0) {
      for (;;) {
        unsigned s = 0;
#pragma unroll
        for (int i = 0; i < 32; ++i)
          s += __hip_atomic_load(&wsu[i * 8], __ATOMIC_RELAXED, __HIP_MEMORY_SCOPE_AGENT);
        if (s >= target) break;
        __builtin_amdgcn_s_sleep(8);
        if (++spins > 5000000u) break;   // catastrophic-only bailout
      }
      __hip_atomic_store(&wsu[256 + phase], 1u, __ATOMIC_RELAXED, __HIP_MEMORY_SCOPE_AGENT);
    } else {
      while (!__hip_atomic_load(&wsu[256 + phase], __ATOMIC_RELAXED, __HIP_MEMORY_SCOPE_AGENT)) {
        __builtin_amdgcn_s_sleep(8);
        if (++spins > 5000000u) break;
      }
    }
  }
  __syncthreads();
}

__global__ __launch_bounds__(256, 8) void mega_k(
    const float* __restrict__ x, const float* __restrict__ cw, const float* __restrict__ cb,
    const float* __restrict__ lw, const float* __restrict__ lb,
    float* __restrict__ out, float* __restrict__ wsf, signed char* __restrict__ qx,
    int nb, int rpb) {
  __shared__ unsigned short hist2D[32 * 256];   // up to 32 rows/block of bin counts
  __shared__ float redS[256];                   // aliased: reduce tree / live hist / j2 LUT
  unsigned* hist = (unsigned*)redS;
  unsigned* wsu = (unsigned*)wsf;
  const int tid = threadIdx.x, blk = blockIdx.x;
  const int lane = tid & 63, wid = tid >> 6;
  const int c = blk & (CC - 1), hh = blk >> 10;   // channel, batch-half

  // ---- ph0: weight amaxes (redundant per block; order-invariant, L2-hit)
  float acw = 0.f;
#pragma unroll
  for (int i = 0; i < 16; ++i) acw = fmaxf(acw, fabsf(cw[tid + 256 * i]));
  acw = bred_max(acw, redS);
  float alw = 0.f;
  for (int i = tid; i < NCLS * CC; i += 256) alw = fmaxf(alw, fabsf(lw[i]));
  alw = bred_max(alw, redS);
  const float s_w = acw / 127.f + 1e-8f;
  const float s_l = alw / 127.f + 1e-8f;

  // ---- ph1: amax(x), 2 coalesced float4 streams per iteration (ILP)
  {
    const float4* p4 = (const float4*)x;
    const long long n4 = NTOT / 4;
    const long long half = (long long)nb * 256;
    float m0 = 0.f, m1 = 0.f;
    for (long long i = (long long)blk * 256 + tid; i < n4; i += half * 2) {
      float4 a = p4[i];
      float4 b = p4[i + half];
      m0 = fmaxf(m0, fmaxf(fmaxf(fabsf(a.x), fabsf(a.y)), fmaxf(fabsf(a.z), fabsf(a.w))));
      m1 = fmaxf(m1, fmaxf(fmaxf(fabsf(b.x), fabsf(b.y)), fmaxf(fabsf(b.z), fabsf(b.w))));
    }
    float m = bred_max(fmaxf(m0, m1), redS);
    if (!tid) gput(&wsf[OF_BM0 + blk], m);
  }
  gbar(wsu, 0, 1u * nb, blk);
  float mm = 0.f;
  for (int i = tid; i < nb; i += 256) mm = fmaxf(mm, gget(&wsf[OF_BM0 + i]));
  const float amax_x = bred_max(mm, redS);
  const float s_x = amax_x / 127.f + 1e-8f, rs_x = 1.f / s_x;
  const float s_xw = s_x * s_w;

  // per-channel conv weights, quantized once into registers
  const float wl0 = qlvl_div(cw[c * 4 + 0], s_w), wl1 = qlvl_div(cw[c * 4 + 1], s_w);
  const float wl2 = qlvl_div(cw[c * 4 + 2], s_w), wl3 = qlvl_div(cw[c * 4 + 3], s_w);
  const float bc = cb[c];

  // ---- ph2: quantize x -> qx (block-local rows), conv, amax|h|
  {
    float mH = 0.f;
    const int t0 = tid * 16;
    for (int k = 0; k < rpb; ++k) {
      const int row = c + ((hh * rpb + k) << 10);
      const float* xr = x + 1LL * row * LL;
      float lv[19];
      if (t0 == 0) { lv[0] = 0.f; lv[1] = 0.f; lv[2] = 0.f; }
      else {
        float4 p = *(const float4*)(xr + t0 - 4);
        lv[0] = qlvl_mul(p.y, rs_x); lv[1] = qlvl_mul(p.z, rs_x); lv[2] = qlvl_mul(p.w, rs_x);
      }
#pragma unroll
      for (int jj = 0; jj < 4; ++jj) {
        float4 v = *(const float4*)(xr + t0 + 4 * jj);
        lv[3 + 4 * jj] = qlvl_mul(v.x, rs_x); lv[4 + 4 * jj] = qlvl_mul(v.y, rs_x);
        lv[5 + 4 * jj] = qlvl_mul(v.z, rs_x); lv[6 + 4 * jj] = qlvl_mul(v.w, rs_x);
      }
      union { int4 v; signed char ch[16]; } pk;
#pragma unroll
      for (int j = 0; j < 16; ++j) {
        pk.ch[j] = (signed char)(int)lv[3 + j];
        float sum = lv[j] * wl0 + lv[j + 1] * wl1 + lv[j + 2] * wl2 + lv[j + 3] * wl3; // exact ints
        float h = fmaf(s_xw, sum, bc);
        mH = fmaxf(mH, fabsf(h));
      }
      if (qx) *(int4*)(qx + 1LL * row * LL + t0) = pk.v;
    }
    mH = bred_max(mH, redS);
    if (!tid) gput(&wsf[OF_BM1 + blk], mH);
  }
  gbar(wsu, 1, 2u * nb, blk);
  mm = 0.f;
  for (int i = tid; i < nb; i += 256) mm = fmaxf(mm, gget(&wsf[OF_BM1 + i]));
  const float amax_h = bred_max(mm, redS);
  const float s_c = amax_h / 127.f + 1e-8f, rs_c = 1.f / s_c;

  // ---- ph3: conv from qx, quantize -> per-row HISTOGRAM of levels (no qc, no LUT)
  bool occ = false;                    // this thread's bin (=tid) seen anywhere?
  {
    hist[tid] = 0u; __syncthreads();
    const int t0 = tid * 16;
    for (int k = 0; k < rpb; ++k) {
      const int row = c + ((hh * rpb + k) << 10);
      float lv[19];
      if (qx) {
        const signed char* qr = qx + 1LL * row * LL;
        if (t0 == 0) { lv[0] = 0.f; lv[1] = 0.f; lv[2] = 0.f; }
        else {
          int pv = *(const int*)(qr + t0 - 4);
          lv[0] = (float)((signed char)(pv >> 8));
          lv[1] = (float)((signed char)(pv >> 16));
          lv[2] = (float)(pv >> 24);
        }
        union { int4 v; signed char ch[16]; } in; in.v = *(const int4*)(qr + t0);
#pragma unroll
        for (int j = 0; j < 16; ++j) lv[3 + j] = (float)in.ch[j];
      } else {
        const float* xr = x + 1LL * row * LL;
        if (t0 == 0) { lv[0] = 0.f; lv[1] = 0.f; lv[2] = 0.f; }
        else {
          float4 p = *(const float4*)(xr + t0 - 4);
          lv[0] = qlvl_mul(p.y, rs_x); lv[1] = qlvl_mul(p.z, rs_x); lv[2] = qlvl_mul(p.w, rs_x);
        }
#pragma unroll
        for (int jj = 0; jj < 4; ++jj) {
          float4 v = *(const float4*)(xr + t0 + 4 * jj);
          lv[3 + 4 * jj] = qlvl_mul(v.x, rs_x); lv[4 + 4 * jj] = qlvl_mul(v.y, rs_x);
          lv[5 + 4 * jj] = qlvl_mul(v.z, rs_x); lv[6 + 4 * jj] = qlvl_mul(v.w, rs_x);
        }
      }
#pragma unroll
      for (int j = 0; j < 16; ++j) {
        float sum = lv[j] * wl0 + lv[j + 1] * wl1 + lv[j + 2] * wl2 + lv[j + 3] * wl3;
        float h = fmaf(s_xw, sum, bc);
        float qf = fminf(fmaxf(rintf(h * rs_c), -128.f), 127.f);
        atomicAdd(&hist[(int)qf + 128], 1u);
      }
      __syncthreads();
      unsigned n = hist[tid];
      hist2D[k * 256 + tid] = (unsigned short)n;
      occ = occ || (n != 0u);
      hist[tid] = 0u;
      __syncthreads();
    }
  }
  // silu-amax = max over occupied bins of |silu(bin_value)| — identical set
  // to the old per-element LUT max (absY formula verbatim).
  const float vbin = (float)(tid - 128) * s_c;
  const float ybin = vbin * (1.f / (1.f + expf(-vbin)));
  {
    float mS = occ ? fabsf(ybin) : 0.f;
    mS = bred_max(mS, redS);
    if (!tid) gput(&wsf[OF_BM2 + blk], mS);
  }
  gbar(wsu, 2, 3u * nb, blk);
  mm = 0.f;
  for (int i = tid; i < nb; i += 256) mm = fmaxf(mm, gget(&wsf[OF_BM2 + i]));
  const float amax_y = bred_max(mm, redS);

  // lut2 levels (verbatim finL math): j2 = integer level, value = j2*s2
  const float s1 = amax_y / 127.f + 1e-8f;
  const float maxj = fminf(fmaxf(rintf(amax_y / s1), -128.f), 127.f);
  const float s2 = (maxj * s1) / 127.f + 1e-8f;
  {
    float y1 = fq_div(ybin, s1);
    float j2 = qlvl_div(y1, s2);       // integer-valued float
    redS[tid] = j2;                    // j2 LUT lives in redS
  }
  __syncthreads();

  // ---- ph4: pooled mean from histograms — exact integer dot per row.
  // sum = Σ n_i*j2_i : every term and partial sum is an integer <= 2^19,
  // exact in fp32 regardless of order. pv = sum*s2/4096.
  {
    float pm = 0.f;
    for (int r = wid; r < rpb; r += 4) {
      float s = 0.f;
#pragma unroll
      for (int kk = 0; kk < 4; ++kk) {
        int b = lane + 64 * kk;
        s += (float)hist2D[r * 256 + b] * redS[b];
      }
      s = wred_sum(s);                 // exact (integers)
      if (lane == 0) {
        const int row = c + ((hh * rpb + r) << 10);
        float pv = s * s2 * (1.f / (float)LL);
        gput(&wsf[OF_POOL + row], pv);
        pm = fmaxf(pm, fabsf(pv));
      }
    }
    __syncthreads();                   // j2 reads done before redS reuse
    pm = bred_max(pm, redS);
    if (!tid) gput(&wsf[OF_BM3 + blk], pm);
  }
  gbar(wsu, 3, 4u * nb, blk);
  mm = 0.f;
  for (int i = tid; i < nb; i += 256) mm = fmaxf(mm, gget(&wsf[OF_BM3 + i]));
  const float aP = bred_max(mm, redS);

  // ---- ph5: head (blocks 0..319), verbatim head_k structure
  if (blk < BB * NCLS) {
    const float s_p = aP / 127.f + 1e-8f;
    const int b = blk / NCLS, n = blk - b * NCLS;
    float sum = 0.f;
    for (int ci = tid; ci < CC; ci += 256)
      sum += fq_div(gget(&wsf[OF_POOL + b * CC + ci]), s_p) * fq_div(lw[n * CC + ci], s_l);
    redS[tid] = sum; __syncthreads();
    for (int s = 128; s; s >>= 1) { if (tid < s) redS[tid] += redS[tid + s]; __syncthreads(); }
    if (!tid) out[b * NCLS + n] = redS[0] + lb[n];
  }
}

extern "C" void kernel_launch(void* const* d_in, const int* in_sizes, int n_in,
                              void* d_out, int out_size, void* d_ws, size_t ws_size,
                              hipStream_t stream) {
  const float* x  = (const float*)d_in[0];
  const float* cw = (const float*)d_in[1];
  const float* cb = (const float*)d_in[2];
  const float* lw = (const float*)d_in[3];
  const float* lb = (const float*)d_in[4];
  float* wsf = (float*)d_ws;
  signed char* qx = (ws_size >= OFFQ + (size_t)NTOT) ? (signed char*)d_ws + OFFQ
                                                     : (signed char*)nullptr;

  // Grid must be fully resident for the barrier. Query real occupancy once;
  // 8 blocks/CU (launch_bounds 256,8 + 17.5KB LDS) -> 2048, else 1024.
  static int nbCached = 0;
  if (nbCached == 0) {
    int maxB = 0;
    if (hipOccupancyMaxActiveBlocksPerMultiprocessor(&maxB, mega_k, 256, 0) != hipSuccess)
      maxB = 4;
    nbCached = (maxB >= 8) ? 2048 : 1024;
  }
  const int nb = nbCached;
  const int rpb = ROWS / nb;   // rows per block: 16 (nb=2048) or 32 (nb=1024)

  // zero barrier counters + flags (workspace is poisoned between iterations)
  hipMemsetAsync(d_ws, 0, 2048, stream);
  hipLaunchKernelGGL(mega_k, dim3(nb), dim3(256), 0, stream,
                     x, cw, cb, lw, lb, (float*)d_out, wsf, qx, nb, rpb);
}